// Round 12
// baseline (354.966 us; speedup 1.0000x reference)
//
#include <hip/hip_runtime.h>
#include <hip/hip_bf16.h>
#include <math.h>

#define CB 4
#define CS 2048
#define CC 1024
#define CH 16
#define CD 64
#define CBS (CB*CS)   // 8192 tokens

typedef unsigned short u16;
typedef __bf16 bf16x8 __attribute__((ext_vector_type(8)));
typedef float f32x4 __attribute__((ext_vector_type(4)));
typedef float f32x16 __attribute__((ext_vector_type(16)));
typedef unsigned short u16x4 __attribute__((ext_vector_type(4)));
typedef unsigned short u16x8 __attribute__((ext_vector_type(8)));
typedef unsigned u32x2 __attribute__((ext_vector_type(2)));

__device__ __forceinline__ u16 f2bf(float f){
  union { float f; unsigned u; } v; v.f = f;
  unsigned r = v.u + 0x7FFFu + ((v.u >> 16) & 1u);   // RNE
  return (u16)(r >> 16);
}
__device__ __forceinline__ unsigned pack2bf(float a, float b){
  __hip_bfloat162 h = __float22bfloat162_rn(make_float2(a, b));
  union { __hip_bfloat162 h; unsigned u; } c; c.h = h; return c.u;
}
__device__ __forceinline__ f32x4 mfma16(bf16x8 a, bf16x8 b, f32x4 c){
  return __builtin_amdgcn_mfma_f32_16x16x32_bf16(a, b, c, 0, 0, 0);
}
__device__ __forceinline__ f32x16 mfma32(bf16x8 a, bf16x8 b, f32x16 c){
  return __builtin_amdgcn_mfma_f32_32x32x16_bf16(a, b, c, 0, 0, 0);
}
// async global->LDS, 16B per lane. lds base must be WAVE-UNIFORM; HW scatters
// lane i to base + i*16B (m104/m108). Global ptr is per-lane.
__device__ __forceinline__ void gload16(const u16* g, u16* lds_base_uniform){
  __builtin_amdgcn_global_load_lds(
      (const __attribute__((address_space(1))) unsigned int*)g,
      (__attribute__((address_space(3))) unsigned int*)lds_base_uniform, 16, 0, 0);
}

// ---------------------------------------------------------------------------
// x fp32 -> bf16 (and zero the 4 entropy accumulators)
// ---------------------------------------------------------------------------
__global__ __launch_bounds__(256) void convert_x_kernel(
    const float* __restrict__ x, u16* __restrict__ xb, float* __restrict__ zero4){
  if (blockIdx.x == 0 && threadIdx.x < 4) zero4[threadIdx.x] = 0.0f;
  size_t i = ((size_t)blockIdx.x*256 + threadIdx.x)*8;
  float4 a = *(const float4*)(x+i);
  float4 b = *(const float4*)(x+i+4);
  u16x8 o = { f2bf(a.x),f2bf(a.y),f2bf(a.z),f2bf(a.w),
              f2bf(b.x),f2bf(b.y),f2bf(b.z),f2bf(b.w) };
  *(u16x8*)(xb+i) = o;
}

// ---------------------------------------------------------------------------
// Transpose + fp32->bf16:  w[K][N] -> wt[N][K]
// ---------------------------------------------------------------------------
template<int K, int N>
__global__ __launch_bounds__(256) void transpose_convert_kernel(
    const float* __restrict__ w, u16* __restrict__ wt){
  __shared__ u16 tile[64][65];
  const int nb = N/64;
  int tk0 = (blockIdx.x / nb) * 64;
  int tn0 = (blockIdx.x % nb) * 64;
  int t = threadIdx.x;
  for (int i = 0; i < 4; i++) {
    int r = i*16 + (t>>4);
    int c = (t&15)*4;
    float4 v = *(const float4*)(w + (size_t)(tk0+r)*N + tn0 + c);
    tile[c+0][r]=f2bf(v.x); tile[c+1][r]=f2bf(v.y);
    tile[c+2][r]=f2bf(v.z); tile[c+3][r]=f2bf(v.w);
  }
  __syncthreads();
  for (int i = 0; i < 4; i++) {
    int r = i*16 + (t>>4);
    int c = (t&15)*4;
    u16x4 o = { tile[r][c+0], tile[r][c+1], tile[r][c+2], tile[r][c+3] };
    *(u16x4*)(wt + (size_t)(tn0+r)*K + tk0 + c) = o;
  }
}

// ---------------------------------------------------------------------------
// V [B,H,S,D] -> V^T [B,H,D,S]
// ---------------------------------------------------------------------------
__global__ __launch_bounds__(256) void transpose_v_kernel(
    const u16* __restrict__ vb, u16* __restrict__ vtb){
  __shared__ u16 tile[64][72];
  int bh = blockIdx.x >> 5;
  int st = blockIdx.x & 31;
  int t = threadIdx.x;
  const u16* src = vb + (size_t)bh*CS*CD + (size_t)st*64*CD;
  int r = t>>2, c = (t&3)*16;
  *(u16x8*)&tile[r][c]   = *(const u16x8*)(src + (size_t)r*CD + c);
  *(u16x8*)&tile[r][c+8] = *(const u16x8*)(src + (size_t)r*CD + c + 8);
  __syncthreads();
  int d = t>>2, s = (t&3)*16;
  u16x8 o0, o1;
  for (int j=0;j<8;j++){ o0[j] = tile[s+j][d]; o1[j] = tile[s+8+j][d]; }
  u16* dst = vtb + (size_t)bh*CD*CS + (size_t)d*CS + st*64 + s;
  *(u16x8*)dst = o0;
  *(u16x8*)(dst+8) = o1;
}

// ---------------------------------------------------------------------------
// GEMM1 (R10-exact, best measured): A direct global->VGPR (wave-exclusive
// rows), B via 3-buffer counted-vmcnt LDS pipeline, BK=32, bl = 24 KiB,
// launch_bounds(256,3). vmcnt(4) main loop, vmcnt(0) tail.
// q outscale folds 1/sqrt(D) AND log2(e) so attention uses raw v_exp_f32.
// ---------------------------------------------------------------------------
__global__ __launch_bounds__(256, 3) void gemm_qkv_ln_kernel(
    const u16* __restrict__ xb, const u16* __restrict__ wqkvT,
    const float* __restrict__ qsc, const float* __restrict__ qbi,
    const float* __restrict__ ksc, const float* __restrict__ kbi,
    u16* __restrict__ qb, u16* __restrict__ kb, u16* __restrict__ vb){
  __shared__ __align__(16) u16 bl[3][128*32];
  int t = threadIdx.x;
  int wv = t >> 6, lane = t & 63, lo = lane & 15, q4 = lane >> 4;
  int m0 = blockIdx.x * 128;
  int n0 = blockIdx.y * 128;
  int lsB = (lane & 3) ^ ((lane >> 3) & 3);      // logical slot for B staging
  const u16* bg0  = wqkvT + (size_t)(n0 + (lane>>2))*CC + lsB*8;
  const u16* agl0 = xb + (size_t)(m0 + wv*32 + lo)*CC + q4*8;
  const u16* agl1 = agl0 + (size_t)16*CC;

  f32x4 acc[2][8];
  #pragma unroll
  for (int i=0;i<2;i++)
    #pragma unroll
    for (int j=0;j<8;j++) acc[i][j] = (f32x4){0.f,0.f,0.f,0.f};

  auto stageB = [&](int buf, int kk){
    #pragma unroll
    for (int cc=0; cc<2; cc++){
      int c = wv*2 + cc;                        // chunk 0..7 (16 rows each)
      gload16(bg0 + (size_t)c*16*CC + kk*32, &bl[buf][c*512]);
    }
  };

  stageB(0, 0);
  stageB(1, 1);
  bf16x8 acur0 = *(const bf16x8*)(agl0);
  bf16x8 acur1 = *(const bf16x8*)(agl1);
  int cur = 0;
  const int akey = (lo >> 1) & 3;

  for (int kk = 0; kk < 32; kk++){
    if (kk < 30){
      asm volatile("s_waitcnt vmcnt(4)" ::: "memory");
      __builtin_amdgcn_s_barrier();
      __builtin_amdgcn_sched_barrier(0);
      int nb = cur + 2; if (nb >= 3) nb -= 3;
      stageB(nb, kk + 2);
    } else if (kk == 30){
      asm volatile("s_waitcnt vmcnt(4)" ::: "memory");
      __builtin_amdgcn_s_barrier();
      __builtin_amdgcn_sched_barrier(0);
    } else {
      asm volatile("s_waitcnt vmcnt(0)" ::: "memory");
      __builtin_amdgcn_s_barrier();
      __builtin_amdgcn_sched_barrier(0);
    }
    // prefetch next A-tile into VGPRs (compiler manages its own waitcnt)
    bf16x8 anxt0, anxt1;
    if (kk < 31){
      anxt0 = *(const bf16x8*)(agl0 + (kk+1)*32);
      anxt1 = *(const bf16x8*)(agl1 + (kk+1)*32);
    } else {
      anxt0 = acur0; anxt1 = acur1;
    }
    const u16* bc = &bl[cur][0];
    int soff = (q4 ^ akey) << 3;
    __builtin_amdgcn_s_setprio(1);
    #pragma unroll
    for (int nt=0; nt<8; nt++){
      bf16x8 b = *(const bf16x8*)&bc[(nt*16 + lo)*32 + soff];
      acc[0][nt] = mfma16(acur0, b, acc[0][nt]);
      acc[1][nt] = mfma16(acur1, b, acc[1][nt]);
    }
    __builtin_amdgcn_s_setprio(0);
    acur0 = anxt0; acur1 = anxt1;
    cur = (cur == 2) ? 0 : cur + 1;
  }

  int three = n0 >> 10;
  int h0 = (n0 & 1023) >> 6;
  const float* scp = (three == 0) ? qsc : ksc;
  const float* bip = (three == 0) ? qbi : kbi;
  // q: fold 1/sqrt(D)=0.125 and log2(e) so attn uses exp2 directly
  float outscale = (three == 0) ? 0.125f * 1.44269504088896f : 1.0f;
  u16* dst = (three == 0) ? qb : (three == 1 ? kb : vb);

  for (int rt = 0; rt < 2; rt++){
    int tg = m0 + wv*32 + rt*16 + q4*4;
    for (int hf = 0; hf < 2; hf++){
      int h = h0 + hf;
      for (int r = 0; r < 4; r++){
        int token = tg + r;
        int bb = token >> 11, ss = token & (CS-1);
        size_t base = (((size_t)(bb*CH + h))*CS + ss)*CD;
        if (three < 2){
          float s1 = 0.f, s2 = 0.f;
          for (int j=0;j<4;j++){ float v = acc[rt][hf*4+j][r]; s1 += v; s2 += v*v; }
          for (int off=8; off>=1; off>>=1){
            s1 += __shfl_xor(s1, off, 16);
            s2 += __shfl_xor(s2, off, 16);
          }
          float mean = s1 * (1.f/64.f);
          float var  = s2 * (1.f/64.f) - mean*mean;
          float rstd = rsqrtf(var + 1e-5f);
          for (int j=0;j<4;j++){
            int d = j*16 + lo;
            float v = (acc[rt][hf*4+j][r] - mean) * rstd * scp[d] + bip[d];
            dst[base + d] = f2bf(v * outscale);
          }
        } else {
          for (int j=0;j<4;j++){
            int d = j*16 + lo;
            dst[base + d] = f2bf(acc[rt][hf*4+j][r]);
          }
        }
      }
    }
  }
}

// ---------------------------------------------------------------------------
// Attention. THIS REV: BARRIER-FREE PRIVATE WAVES. Blocks = 64 threads =
// 1 wave, 32 q-rows each (grid 4096). Each wave stages its OWN K/V tile
// (KVBLK=32) into private double-buffered LDS: kl[2][32*64] + vl[2][64*32]
// = 16384 B/block -> exactly 10 blocks/CU (160 KB). ZERO s_barriers.
// Rationale: 5 structural variants all pinned at 131-134 us with every pipe
// <50%; the shared invariant was the block-wide barrier per KV-tile coupling
// 16 waves in lock-step. Here waves self-pace on their own vmcnt(8)
// (2 tiles in flight, 8 gload16 each). Buffer reuse is same-wave ordered:
// frag ds_reads -> explicit lgkmcnt(0)+sched_barrier(0) -> re-stage same
// buffer -> MFMA/softmax (DMA issue latency hides under compute).
// Swizzle maps bit-identical to the R5/R6-proven forms:
//   K: chunk c rows c*8+(l>>3), fetch logical slot (l&7)^(l>>3)^c;
//      read phys = (2ks+hi)^(col&7)^(col>>3)  [2 lanes/bank = free]
//   V: chunk c rows c*16+(l>>2), fetch logical (l&3)^((l>>2)&3);
//      read phys = (2ks+hi)^(col&3)           [known benign 2x]
// vmcnt ledger: prologue 16 out; iters 0..62 wait vmcnt(8) (own tile t
// landed, t+1 flying); iter 63 vmcnt(0). T12 in-reg P, exp2 softmax,
// setprio, shfl-invz epilogue all kept.
// ---------------------------------------------------------------------------
__global__ __launch_bounds__(64, 2) void attention_kernel(
    const u16* __restrict__ qb, const u16* __restrict__ kb,
    const u16* __restrict__ vtb, u16* __restrict__ attnb, float* __restrict__ ent){
  __shared__ __align__(16) u16 kl[2][32*64];    // [buf][sk][dslot^] 4 KB each
  __shared__ __align__(16) u16 vl[2][64*32];    // [buf][d][skslot^] 4 KB each
  int lane = threadIdx.x & 63;
  int col = lane & 31, hi = lane >> 5;
  // XCD swizzle: block n runs on XCD n%8; each XCD owns heads == xc (mod 8).
  int n = blockIdx.x;
  int xc = n & 7, j = n >> 3;        // j in [0,512)
  int qt = j & 63;                   // 64 q-tiles (32 rows) per head
  int bh = xc + 8*(j >> 6);
  int bI = bh >> 4;
  int q0w = qt*32;
  const u16* qbp = qb  + (size_t)bh * CS * CD;
  const u16* kbp = kb  + (size_t)bh * CS * CD;
  const u16* vbp = vtb + (size_t)bh * CD * CS;

  // Q B-frags, held for the whole kernel
  bf16x8 qf[4];
  #pragma unroll
  for (int ks=0;ks<4;ks++)
    qf[ks] = *(const bf16x8*)(qbp + (size_t)(q0w + col)*CD + ks*16 + hi*8);

  f32x16 o[2];
  #pragma unroll
  for (int nt=0;nt<2;nt++)
    #pragma unroll
    for (int i=0;i<16;i++) o[nt][i] = 0.f;
  float zacc = 0.f, tacc = 0.f;

  int srow8  = lane >> 3, sl8 = lane & 7;
  int srow16 = lane >> 2, sl4 = lane & 3;

  // stage tile into private buffer: 8 gload16 (K: 4 chunks, V: 4 chunks)
  auto stage = [&](int b, int tile){
    int skn = tile*32;
    #pragma unroll
    for (int c=0;c<4;c++){
      int kr = c*8 + srow8;
      int ks_ = sl8 ^ srow8 ^ c;
      gload16(kbp + (size_t)(skn + kr)*CD + ks_*8, &kl[b][c*512]);
    }
    #pragma unroll
    for (int c=0;c<4;c++){
      int vr = c*16 + srow16;
      int vs = sl4 ^ (srow16 & 3);
      gload16(vbp + (size_t)vr*CS + skn + vs*8, &vl[b][c*512]);
    }
  };

  stage(0, 0);
  stage(1, 1);                       // 16 outstanding

  const int kkey = (col & 7) ^ (col >> 3);
  const int vkey = (col & 3);

  for (int it = 0; it < 64; it++){
    if (it < 63){
      asm volatile("s_waitcnt vmcnt(8)" ::: "memory");
    } else {
      asm volatile("s_waitcnt vmcnt(0)" ::: "memory");
    }
    const int cur = it & 1;
    const u16* kc = &kl[cur][0];
    const u16* vc = &vl[cur][0];

    // frag reads from private LDS
    bf16x8 kfr[4], vfr[2][2];
    #pragma unroll
    for (int ks=0;ks<4;ks++)
      kfr[ks] = *(const bf16x8*)&kc[col*64 + (((2*ks+hi) ^ kkey)<<3)];
    #pragma unroll
    for (int nt=0;nt<2;nt++)
      #pragma unroll
      for (int ks=0;ks<2;ks++)
        vfr[nt][ks] = *(const bf16x8*)&vc[(nt*32+col)*32 + (((ks*2+hi) ^ vkey)<<3)];

    // all frag reads complete BEFORE re-staging the same buffer (same-wave
    // ordering; no barrier needed). sched_barrier pins the fence (rule #18).
    asm volatile("s_waitcnt lgkmcnt(0)" ::: "memory");
    __builtin_amdgcn_sched_barrier(0);
    if (it < 62) stage(cur, it + 2);

    // S^T (32 sk x 32 q) = K . Q^T
    f32x16 sf;
    #pragma unroll
    for (int i=0;i<16;i++) sf[i] = 0.f;
    __builtin_amdgcn_s_setprio(1);
    #pragma unroll
    for (int ks=0;ks<4;ks++)
      sf = mfma32(kfr[ks], qf[ks], sf);
    __builtin_amdgcn_s_setprio(0);

    // fused exp2 + Z/T partials + in-register P-frag build + PV.
    #pragma unroll
    for (int ksl=0; ksl<2; ksl++){
      float p[2][4];
      #pragma unroll
      for (int gg=0; gg<2; gg++){
        int g = 2*ksl + gg;
        float l0 = sf[g*4+0], l1 = sf[g*4+1],
              l2 = sf[g*4+2], l3 = sf[g*4+3];
        float p0 = __builtin_amdgcn_exp2f(l0);
        float p1 = __builtin_amdgcn_exp2f(l1);
        float p2 = __builtin_amdgcn_exp2f(l2);
        float p3 = __builtin_amdgcn_exp2f(l3);
        zacc += (p0+p1)+(p2+p3);
        tacc += (p0*l0+p1*l1)+(p2*l2+p3*l3);
        p[gg][0]=p0; p[gg][1]=p1; p[gg][2]=p2; p[gg][3]=p3;
      }
      unsigned x0 = pack2bf(p[0][0], p[0][1]);
      unsigned x1 = pack2bf(p[0][2], p[0][3]);
      unsigned y0 = pack2bf(p[1][0], p[1][1]);
      unsigned y1 = pack2bf(p[1][2], p[1][3]);
      u32x2 s0 = __builtin_amdgcn_permlane32_swap(x0, y0, false, false);
      u32x2 s1 = __builtin_amdgcn_permlane32_swap(x1, y1, false, false);
      union { unsigned u[4]; bf16x8 v; } ap;
      ap.u[0] = s0[0]; ap.u[1] = s1[0]; ap.u[2] = s0[1]; ap.u[3] = s1[1];
      __builtin_amdgcn_s_setprio(1);
      o[0] = mfma32(ap.v, vfr[0][ksl], o[0]);
      o[1] = mfma32(ap.v, vfr[1][ksl], o[1]);
      __builtin_amdgcn_s_setprio(0);
    }
  }

  // finalize: combine hi-halves of Z/T (lane col owns q-row col, both halves)
  float z2 = zacc + __shfl_xor(zacc, 32);
  float t2 = tacc + __shfl_xor(tacc, 32);
  float invz = 1.f / z2;

  // entropy (log2 domain): s_nat = ln2 * (log2(Z) - T2/Z)
  float srowv = 0.69314718055995f * (__builtin_amdgcn_logf(z2) - t2 * invz);
  float ev = (hi == 0) ? srowv : 0.f;
  for (int off=1; off<=32; off<<=1) ev += __shfl_xor(ev, off);
  if (lane == 0){
    float entscale = 1.0f / ((float)CH * (float)CS * logf((float)CS));
    atomicAdd(&ent[bI], ev * entscale);
  }

  // inv-Z broadcast via shfl: lane qrow (hi=0 image) owns invz for q-row qrow.
  float izv[4][4];
  #pragma unroll
  for (int g=0; g<4; g++)
    #pragma unroll
    for (int r=0; r<4; r++)
      izv[g][r] = __shfl(invz, 8*g + 4*hi + r);

  // O write, head-major [B,H,S,D] (C: col=d-within-32, row=(reg&3)+8*(reg>>2)+4*hi)
  u16* obase = attnb + ((size_t)bh*CS + q0w)*CD;
  #pragma unroll
  for (int nt=0;nt<2;nt++){
    #pragma unroll
    for (int g=0;g<4;g++){
      #pragma unroll
      for (int r=0;r<4;r++){
        int qrow = 8*g + 4*hi + r;
        obase[(size_t)qrow*CD + nt*32 + col] = f2bf(o[nt][g*4+r] * izv[g][r]);
      }
    }
  }
}

// ---------------------------------------------------------------------------
// GEMM3 (R10-exact): A direct global->VGPR prefetch; B 3-buffer counted-vmcnt
// LDS pipeline (24 KiB), BK=32, launch_bounds(256,3).
// attnH is head-major [B,H,S,D]; K-tile kk = head kk>>1, d-half (kk&1)*32.
// ---------------------------------------------------------------------------
__global__ __launch_bounds__(256, 3) void gemm_out_kernel(
    const u16* __restrict__ attnH, const u16* __restrict__ wprojT,
    float* __restrict__ out){
  __shared__ __align__(16) u16 bl[3][128*32];
  int t = threadIdx.x;
  int wv = t >> 6, lane = t & 63, lo = lane & 15, q4 = lane >> 4;
  int m0 = blockIdx.x * 128;
  int n0 = blockIdx.y * 128;
  int b  = m0 >> 11, s0 = m0 & (CS-1);
  int lsB = (lane & 3) ^ ((lane >> 3) & 3);
  const u16* bg0 = wprojT + (size_t)(n0 + (lane>>2))*CC + lsB*8;
  // A base for this lane's rows (head/d-half offset added per kk)
  const u16* agl0 = attnH + ((size_t)(b*CH)*CS + s0 + wv*32 + lo)*CD + q4*8;
  const u16* agl1 = agl0 + (size_t)16*CD;

  f32x4 acc[2][8];
  #pragma unroll
  for (int i=0;i<2;i++)
    #pragma unroll
    for (int j=0;j<8;j++) acc[i][j] = (f32x4){0.f,0.f,0.f,0.f};

  auto aoff = [&](int kk) -> size_t {
    return (size_t)(kk >> 1)*CS*CD + (size_t)(kk & 1)*32;
  };
  auto stageB = [&](int buf, int kk){
    #pragma unroll
    for (int cc=0; cc<2; cc++){
      int c = wv*2 + cc;
      gload16(bg0 + (size_t)c*16*CC + kk*32, &bl[buf][c*512]);
    }
  };

  stageB(0, 0);
  stageB(1, 1);
  bf16x8 acur0 = *(const bf16x8*)(agl0);
  bf16x8 acur1 = *(const bf16x8*)(agl1);
  int cur = 0;
  const int akey = (lo >> 1) & 3;

  for (int kk = 0; kk < 32; kk++){
    if (kk < 30){
      asm volatile("s_waitcnt vmcnt(4)" ::: "memory");
      __builtin_amdgcn_s_barrier();
      __builtin_amdgcn_sched_barrier(0);
      int nb = cur + 2; if (nb >= 3) nb -= 3;
      stageB(nb, kk + 2);
    } else if (kk == 30){
      asm volatile("s_waitcnt vmcnt(4)" ::: "memory");
      __builtin_amdgcn_s_barrier();
      __builtin_amdgcn_sched_barrier(0);
    } else {
      asm volatile("s_waitcnt vmcnt(0)" ::: "memory");
      __builtin_amdgcn_s_barrier();
      __builtin_amdgcn_sched_barrier(0);
    }
    bf16x8 anxt0, anxt1;
    if (kk < 31){
      size_t ao = aoff(kk + 1);
      anxt0 = *(const bf16x8*)(agl0 + ao);
      anxt1 = *(const bf16x8*)(agl1 + ao);
    } else {
      anxt0 = acur0; anxt1 = acur1;
    }
    const u16* bc = &bl[cur][0];
    int soff = (q4 ^ akey) << 3;
    __builtin_amdgcn_s_setprio(1);
    #pragma unroll
    for (int nt=0; nt<8; nt++){
      bf16x8 b2 = *(const bf16x8*)&bc[(nt*16 + lo)*32 + soff];
      acc[0][nt] = mfma16(acur0, b2, acc[0][nt]);
      acc[1][nt] = mfma16(acur1, b2, acc[1][nt]);
    }
    __builtin_amdgcn_s_setprio(0);
    acur0 = anxt0; acur1 = anxt1;
    cur = (cur == 2) ? 0 : cur + 1;
  }

  for (int rt=0;rt<2;rt++){
    for (int r=0;r<4;r++){
      int row = m0 + wv*32 + rt*16 + q4*4 + r;
      for (int nt=0;nt<8;nt++)
        out[(size_t)row*CC + n0 + nt*16 + lo] = acc[rt][nt][r];
    }
  }
}

// ---------------------------------------------------------------------------
extern "C" void kernel_launch(void* const* d_in, const int* in_sizes, int n_in,
                              void* d_out, int out_size, void* d_ws, size_t ws_size,
                              hipStream_t stream) {
  const float* x      = (const float*)d_in[0];
  const float* w_qkv  = (const float*)d_in[1];
  const float* w_proj = (const float*)d_in[2];
  const float* q_scale= (const float*)d_in[3];
  const float* q_bias = (const float*)d_in[4];
  const float* k_scale= (const float*)d_in[5];
  const float* k_bias = (const float*)d_in[6];
  float* out = (float*)d_out;
  float* ent = out + (size_t)CBS * CC;

  // workspace: 75.5 MB total, with lifetime-based aliasing:
  //   xb slot reused as vbT; vb slot reused as attn (both [B,H,S,D]).
  u16* xb     = (u16*)d_ws;                       // [8192][1024]  (later: vbT [B,H,D,S])
  u16* wqkvT  = xb     + (size_t)CBS*CC;          // [3072][1024]
  u16* wprojT = wqkvT  + (size_t)3*CC*CC;         // [1024][1024]
  u16* qb     = wprojT + (size_t)CC*CC;           // [B,H,S,D]
  u16* kb     = qb + (size_t)CB*CH*CS*CD;
  u16* vb     = kb + (size_t)CB*CH*CS*CD;         // (later: attnH [B,H,S,D])
  u16* vbT    = xb;
  u16* attn   = vb;

  convert_x_kernel<<<dim3(CBS*CC/(256*8)), 256, 0, stream>>>(x, xb, ent);
  transpose_convert_kernel<CC, 3*CC><<<dim3((CC/64)*(3*CC/64)), 256, 0, stream>>>(w_qkv, wqkvT);
  transpose_convert_kernel<CC, CC><<<dim3((CC/64)*(CC/64)), 256, 0, stream>>>(w_proj, wprojT);
  gemm_qkv_ln_kernel<<<dim3(CBS/128, 3*CC/128), 256, 0, stream>>>(
      xb, wqkvT, q_scale, q_bias, k_scale, k_bias, qb, kb, vb);
  transpose_v_kernel<<<dim3(CB*CH*(CS/64)), 256, 0, stream>>>(vb, vbT);
  attention_kernel<<<dim3(CB*CH*(CS/32)), 64, 0, stream>>>(qb, kb, vbT, attn, ent);
  gemm_out_kernel<<<dim3(CBS/128, CC/128), 256, 0, stream>>>(attn, wprojT, out);
}

// Round 13
// 323.276 us; speedup vs baseline: 1.0980x; 1.0980x over previous
//
#include <hip/hip_runtime.h>
#include <hip/hip_bf16.h>
#include <math.h>

#define CB 4
#define CS 2048
#define CC 1024
#define CH 16
#define CD 64
#define CBS (CB*CS)   // 8192 tokens

typedef unsigned short u16;
typedef __bf16 bf16x8 __attribute__((ext_vector_type(8)));
typedef float f32x4 __attribute__((ext_vector_type(4)));
typedef float f32x16 __attribute__((ext_vector_type(16)));
typedef unsigned short u16x4 __attribute__((ext_vector_type(4)));
typedef unsigned short u16x8 __attribute__((ext_vector_type(8)));
typedef unsigned u32x2 __attribute__((ext_vector_type(2)));

__device__ __forceinline__ u16 f2bf(float f){
  union { float f; unsigned u; } v; v.f = f;
  unsigned r = v.u + 0x7FFFu + ((v.u >> 16) & 1u);   // RNE
  return (u16)(r >> 16);
}
__device__ __forceinline__ unsigned pack2bf(float a, float b){
  __hip_bfloat162 h = __float22bfloat162_rn(make_float2(a, b));
  union { __hip_bfloat162 h; unsigned u; } c; c.h = h; return c.u;
}
__device__ __forceinline__ f32x4 mfma16(bf16x8 a, bf16x8 b, f32x4 c){
  return __builtin_amdgcn_mfma_f32_16x16x32_bf16(a, b, c, 0, 0, 0);
}
__device__ __forceinline__ f32x16 mfma32(bf16x8 a, bf16x8 b, f32x16 c){
  return __builtin_amdgcn_mfma_f32_32x32x16_bf16(a, b, c, 0, 0, 0);
}
// async global->LDS, 16B per lane. lds base must be WAVE-UNIFORM; HW scatters
// lane i to base + i*16B (m104/m108). Global ptr is per-lane.
__device__ __forceinline__ void gload16(const u16* g, u16* lds_base_uniform){
  __builtin_amdgcn_global_load_lds(
      (const __attribute__((address_space(1))) unsigned int*)g,
      (__attribute__((address_space(3))) unsigned int*)lds_base_uniform, 16, 0, 0);
}

// ---------------------------------------------------------------------------
// x fp32 -> bf16 (and zero the 4 entropy accumulators)
// ---------------------------------------------------------------------------
__global__ __launch_bounds__(256) void convert_x_kernel(
    const float* __restrict__ x, u16* __restrict__ xb, float* __restrict__ zero4){
  if (blockIdx.x == 0 && threadIdx.x < 4) zero4[threadIdx.x] = 0.0f;
  size_t i = ((size_t)blockIdx.x*256 + threadIdx.x)*8;
  float4 a = *(const float4*)(x+i);
  float4 b = *(const float4*)(x+i+4);
  u16x8 o = { f2bf(a.x),f2bf(a.y),f2bf(a.z),f2bf(a.w),
              f2bf(b.x),f2bf(b.y),f2bf(b.z),f2bf(b.w) };
  *(u16x8*)(xb+i) = o;
}

// ---------------------------------------------------------------------------
// Transpose + fp32->bf16:  w[K][N] -> wt[N][K]
// ---------------------------------------------------------------------------
template<int K, int N>
__global__ __launch_bounds__(256) void transpose_convert_kernel(
    const float* __restrict__ w, u16* __restrict__ wt){
  __shared__ u16 tile[64][65];
  const int nb = N/64;
  int tk0 = (blockIdx.x / nb) * 64;
  int tn0 = (blockIdx.x % nb) * 64;
  int t = threadIdx.x;
  for (int i = 0; i < 4; i++) {
    int r = i*16 + (t>>4);
    int c = (t&15)*4;
    float4 v = *(const float4*)(w + (size_t)(tk0+r)*N + tn0 + c);
    tile[c+0][r]=f2bf(v.x); tile[c+1][r]=f2bf(v.y);
    tile[c+2][r]=f2bf(v.z); tile[c+3][r]=f2bf(v.w);
  }
  __syncthreads();
  for (int i = 0; i < 4; i++) {
    int r = i*16 + (t>>4);
    int c = (t&15)*4;
    u16x4 o = { tile[r][c+0], tile[r][c+1], tile[r][c+2], tile[r][c+3] };
    *(u16x4*)(wt + (size_t)(tn0+r)*K + tk0 + c) = o;
  }
}

// ---------------------------------------------------------------------------
// GEMM1: qkv = xb @ wqkvT^T (R10-exact main loop: A direct global->VGPR,
// B via 3-buffer counted-vmcnt LDS pipeline, BK=32, bl = 24 KiB,
// launch_bounds(256,3); vmcnt(4) main, vmcnt(0) tail).
// THIS REV: v-branch epilogue writes V DIRECTLY TRANSPOSED to [B,H,D,S]
// via LDS transpose (reusing bl as a 64x132 u16 tile, 16.9 KB < 24 KiB),
// eliminating the separate transpose_v kernel and its 32 MB round trip.
// q outscale folds 1/sqrt(D) AND log2(e) so attention uses raw v_exp_f32.
// ---------------------------------------------------------------------------
__global__ __launch_bounds__(256, 3) void gemm_qkv_ln_kernel(
    const u16* __restrict__ xb, const u16* __restrict__ wqkvT,
    const float* __restrict__ qsc, const float* __restrict__ qbi,
    const float* __restrict__ ksc, const float* __restrict__ kbi,
    u16* __restrict__ qb, u16* __restrict__ kb, u16* __restrict__ vtb){
  __shared__ __align__(16) u16 bl[3][128*32];
  int t = threadIdx.x;
  int wv = t >> 6, lane = t & 63, lo = lane & 15, q4 = lane >> 4;
  int m0 = blockIdx.x * 128;
  int n0 = blockIdx.y * 128;
  int lsB = (lane & 3) ^ ((lane >> 3) & 3);      // logical slot for B staging
  const u16* bg0  = wqkvT + (size_t)(n0 + (lane>>2))*CC + lsB*8;
  const u16* agl0 = xb + (size_t)(m0 + wv*32 + lo)*CC + q4*8;
  const u16* agl1 = agl0 + (size_t)16*CC;

  f32x4 acc[2][8];
  #pragma unroll
  for (int i=0;i<2;i++)
    #pragma unroll
    for (int j=0;j<8;j++) acc[i][j] = (f32x4){0.f,0.f,0.f,0.f};

  auto stageB = [&](int buf, int kk){
    #pragma unroll
    for (int cc=0; cc<2; cc++){
      int c = wv*2 + cc;                        // chunk 0..7 (16 rows each)
      gload16(bg0 + (size_t)c*16*CC + kk*32, &bl[buf][c*512]);
    }
  };

  stageB(0, 0);
  stageB(1, 1);
  bf16x8 acur0 = *(const bf16x8*)(agl0);
  bf16x8 acur1 = *(const bf16x8*)(agl1);
  int cur = 0;
  const int akey = (lo >> 1) & 3;

  for (int kk = 0; kk < 32; kk++){
    if (kk < 30){
      asm volatile("s_waitcnt vmcnt(4)" ::: "memory");
      __builtin_amdgcn_s_barrier();
      __builtin_amdgcn_sched_barrier(0);
      int nb = cur + 2; if (nb >= 3) nb -= 3;
      stageB(nb, kk + 2);
    } else if (kk == 30){
      asm volatile("s_waitcnt vmcnt(4)" ::: "memory");
      __builtin_amdgcn_s_barrier();
      __builtin_amdgcn_sched_barrier(0);
    } else {
      asm volatile("s_waitcnt vmcnt(0)" ::: "memory");
      __builtin_amdgcn_s_barrier();
      __builtin_amdgcn_sched_barrier(0);
    }
    // prefetch next A-tile into VGPRs (compiler manages its own waitcnt)
    bf16x8 anxt0, anxt1;
    if (kk < 31){
      anxt0 = *(const bf16x8*)(agl0 + (kk+1)*32);
      anxt1 = *(const bf16x8*)(agl1 + (kk+1)*32);
    } else {
      anxt0 = acur0; anxt1 = acur1;
    }
    const u16* bc = &bl[cur][0];
    int soff = (q4 ^ akey) << 3;
    __builtin_amdgcn_s_setprio(1);
    #pragma unroll
    for (int nt=0; nt<8; nt++){
      bf16x8 b = *(const bf16x8*)&bc[(nt*16 + lo)*32 + soff];
      acc[0][nt] = mfma16(acur0, b, acc[0][nt]);
      acc[1][nt] = mfma16(acur1, b, acc[1][nt]);
    }
    __builtin_amdgcn_s_setprio(0);
    acur0 = anxt0; acur1 = anxt1;
    cur = (cur == 2) ? 0 : cur + 1;
  }

  int three = n0 >> 10;
  int h0 = (n0 & 1023) >> 6;
  int bb = m0 >> 11, ss0 = m0 & (CS-1);

  if (three < 2){
    const float* scp = (three == 0) ? qsc : ksc;
    const float* bip = (three == 0) ? qbi : kbi;
    // q: fold 1/sqrt(D)=0.125 and log2(e) so attn uses exp2 directly
    float outscale = (three == 0) ? 0.125f * 1.44269504088896f : 1.0f;
    u16* dst = (three == 0) ? qb : kb;

    for (int rt = 0; rt < 2; rt++){
      int tg = m0 + wv*32 + rt*16 + q4*4;
      for (int hf = 0; hf < 2; hf++){
        int h = h0 + hf;
        for (int r = 0; r < 4; r++){
          int token = tg + r;
          int ss = token & (CS-1);
          size_t base = (((size_t)(bb*CH + h))*CS + ss)*CD;
          float s1 = 0.f, s2 = 0.f;
          for (int j=0;j<4;j++){ float v = acc[rt][hf*4+j][r]; s1 += v; s2 += v*v; }
          for (int off=8; off>=1; off>>=1){
            s1 += __shfl_xor(s1, off, 16);
            s2 += __shfl_xor(s2, off, 16);
          }
          float mean = s1 * (1.f/64.f);
          float var  = s2 * (1.f/64.f) - mean*mean;
          float rstd = rsqrtf(var + 1e-5f);
          for (int j=0;j<4;j++){
            int d = j*16 + lo;
            float v = (acc[rt][hf*4+j][r] - mean) * rstd * scp[d] + bip[d];
            dst[base + d] = f2bf(v * outscale);
          }
        }
      }
    }
  } else {
    // v: write directly transposed to vtb [B,H,D,S] via LDS transpose.
    // Reuse bl staging memory as a [64][132] u16 tile (16.9 KB < 24 KiB).
    u16* tl = (u16*)&bl[0][0];
    for (int hf = 0; hf < 2; hf++){
      __syncthreads();   // protect bl main-loop reads (hf=0) / prior tl reads
      #pragma unroll
      for (int rt = 0; rt < 2; rt++){
        int tok = wv*32 + rt*16 + q4*4;
        #pragma unroll
        for (int j = 0; j < 4; j++){
          int d = j*16 + lo;
          #pragma unroll
          for (int r = 0; r < 4; r++)
            tl[d*132 + tok + r] = f2bf(acc[rt][hf*4+j][r]);
        }
      }
      __syncthreads();
      int h = h0 + hf;
      u16* vt = vtb + (((size_t)(bb*CH + h))*CD)*CS + ss0;
      int row = t >> 2, c0 = (t & 3) * 32;
      #pragma unroll
      for (int cc = 0; cc < 32; cc += 8){
        u16x8 o;
        #pragma unroll
        for (int jj=0;jj<8;jj++) o[jj] = tl[row*132 + c0 + cc + jj];
        *(u16x8*)(vt + (size_t)row*CS + c0 + cc) = o;
      }
    }
  }
}

// ---------------------------------------------------------------------------
// Attention (R10-exact -- best measured, 132.5 us; frozen):
// KVBLK=32, shared 3-buffer counted-vmcnt (2 tiles in flight), LDS 24576 B,
// T12 in-reg P, exp2-domain softmax, setprio, shfl-invz epilogue.
// Known issue kept as-is: V-read 4-slot map has ~2x phase conflicts (1.26e7)
// -- measured zero dur impact vs conflict-free variant (R5 vs R6).
// R12 lesson: barrier-free 1-wave blocks REGRESSED (165 us, occ 18%) --
// the block barrier was never the cost; attention is VALU+latency pinned.
// ---------------------------------------------------------------------------
__global__ __launch_bounds__(256, 2) void attention_kernel(
    const u16* __restrict__ qb, const u16* __restrict__ kb,
    const u16* __restrict__ vtb, u16* __restrict__ attnb, float* __restrict__ ent){
  __shared__ __align__(16) u16 kl[3][32*64];    // [buf][sk][dslot^] 4 KB each
  __shared__ __align__(16) u16 vl[3][64*32];    // [buf][d][skslot^] 4 KB each
  int t = threadIdx.x;
  int wv = t >> 6, lane = t & 63;
  int col = lane & 31, hi = lane >> 5;
  // XCD swizzle: block n runs on XCD n%8; give each XCD 8 whole (b,h) heads.
  int n = blockIdx.x;
  int xc = n & 7, j = n >> 3;
  int bh = xc + 8*(j >> 4);
  int qt = j & 15;
  int bI = bh >> 4;
  int q0w = qt*128 + wv*32;
  const u16* qbp = qb  + (size_t)bh * CS * CD;
  const u16* kbp = kb  + (size_t)bh * CS * CD;
  const u16* vbp = vtb + (size_t)bh * CD * CS;

  // staging lane maps
  int srow8  = lane >> 3, sl8 = lane & 7;    // K chunk: 8 rows x 8 slots
  int srow16 = lane >> 2, sl4 = lane & 3;    // V chunk: 16 rows x 4 slots

  // Q B-frags, held for the whole kernel
  bf16x8 qf[4];
  #pragma unroll
  for (int ks=0;ks<4;ks++)
    qf[ks] = *(const bf16x8*)(qbp + (size_t)(q0w + col)*CD + ks*16 + hi*8);

  f32x16 o[2];
  #pragma unroll
  for (int nt=0;nt<2;nt++)
    #pragma unroll
    for (int i=0;i<16;i++) o[nt][i] = 0.f;
  float zacc = 0.f, tacc = 0.f;

  // stage tile `tile` into buffer `buf` (2 gload16/wave: 1 K-chunk + 1 V-chunk)
  auto stage = [&](int buf, int tile){
    int skn = tile*32;
    int krow  = wv*8 + srow8;
    int kslot = sl8 ^ srow8 ^ wv;
    gload16(kbp + (size_t)(skn + krow)*CD + kslot*8, &kl[buf][wv*512]);
    int vrow  = wv*16 + srow16;
    int vslot = sl4 ^ (srow16 & 3);
    gload16(vbp + (size_t)vrow*CS + skn + vslot*8, &vl[buf][wv*512]);
  };

  // prologue: 2 tiles in flight (4 loads/wave outstanding)
  stage(0, 0);
  stage(1, 1);

  const int kkey = (col & 7) ^ (col >> 3);   // K frag-read swizzle key
  const int vkey = (col & 3);                // V frag-read swizzle key
  int cur = 0;

  for (int it = 0; it < 64; it++){
    if (it < 62){
      asm volatile("s_waitcnt vmcnt(2)" ::: "memory");
      __builtin_amdgcn_s_barrier();
      __builtin_amdgcn_sched_barrier(0);
      int nb = cur + 2; if (nb >= 3) nb -= 3;
      stage(nb, it + 2);
    } else if (it == 62){
      asm volatile("s_waitcnt vmcnt(2)" ::: "memory");
      __builtin_amdgcn_s_barrier();
      __builtin_amdgcn_sched_barrier(0);
    } else {
      asm volatile("s_waitcnt vmcnt(0)" ::: "memory");
      __builtin_amdgcn_s_barrier();
      __builtin_amdgcn_sched_barrier(0);
    }
    const u16* kc = &kl[cur][0];
    const u16* vc = &vl[cur][0];

    // frag reads from LDS (swizzled addresses)
    bf16x8 kfr[4], vfr[2][2];
    #pragma unroll
    for (int ks=0;ks<4;ks++)
      kfr[ks] = *(const bf16x8*)&kc[col*64 + (((2*ks+hi) ^ kkey)<<3)];
    #pragma unroll
    for (int nt=0;nt<2;nt++)
      #pragma unroll
      for (int ks=0;ks<2;ks++)
        vfr[nt][ks] = *(const bf16x8*)&vc[(nt*32+col)*32 + (((ks*2+hi) ^ vkey)<<3)];

    // S^T (32 sk x 32 q) = K . Q^T
    f32x16 sf;
    #pragma unroll
    for (int i=0;i<16;i++) sf[i] = 0.f;
    __builtin_amdgcn_s_setprio(1);
    #pragma unroll
    for (int ks=0;ks<4;ks++)
      sf = mfma32(kfr[ks], qf[ks], sf);
    __builtin_amdgcn_s_setprio(0);

    // fused exp2 + Z/T partials + in-register P-frag build + PV.
    #pragma unroll
    for (int ksl=0; ksl<2; ksl++){
      float p[2][4];
      #pragma unroll
      for (int gg=0; gg<2; gg++){
        int g = 2*ksl + gg;
        float l0 = sf[g*4+0], l1 = sf[g*4+1],
              l2 = sf[g*4+2], l3 = sf[g*4+3];
        float p0 = __builtin_amdgcn_exp2f(l0);
        float p1 = __builtin_amdgcn_exp2f(l1);
        float p2 = __builtin_amdgcn_exp2f(l2);
        float p3 = __builtin_amdgcn_exp2f(l3);
        zacc += (p0+p1)+(p2+p3);
        tacc += (p0*l0+p1*l1)+(p2*l2+p3*l3);
        p[gg][0]=p0; p[gg][1]=p1; p[gg][2]=p2; p[gg][3]=p3;
      }
      unsigned x0 = pack2bf(p[0][0], p[0][1]);
      unsigned x1 = pack2bf(p[0][2], p[0][3]);
      unsigned y0 = pack2bf(p[1][0], p[1][1]);
      unsigned y1 = pack2bf(p[1][2], p[1][3]);
      u32x2 s0 = __builtin_amdgcn_permlane32_swap(x0, y0, false, false);
      u32x2 s1 = __builtin_amdgcn_permlane32_swap(x1, y1, false, false);
      union { unsigned u[4]; bf16x8 v; } ap;
      ap.u[0] = s0[0]; ap.u[1] = s1[0]; ap.u[2] = s0[1]; ap.u[3] = s1[1];
      __builtin_amdgcn_s_setprio(1);
      o[0] = mfma32(ap.v, vfr[0][ksl], o[0]);
      o[1] = mfma32(ap.v, vfr[1][ksl], o[1]);
      __builtin_amdgcn_s_setprio(0);
    }
    cur = (cur == 2) ? 0 : cur + 1;
  }

  // finalize: combine hi-halves of Z/T (lane col owns q-row col, both halves)
  float z2 = zacc + __shfl_xor(zacc, 32);
  float t2 = tacc + __shfl_xor(tacc, 32);
  float invz = 1.f / z2;

  // entropy (log2 domain): s_nat = ln2 * (log2(Z) - T2/Z)
  float srowv = 0.69314718055995f * (__builtin_amdgcn_logf(z2) - t2 * invz);
  float ev = (hi == 0) ? srowv : 0.f;
  for (int off=1; off<=32; off<<=1) ev += __shfl_xor(ev, off);
  if (lane == 0){
    float entscale = 1.0f / ((float)CH * (float)CS * logf((float)CS));
    atomicAdd(&ent[bI], ev * entscale);
  }

  // inv-Z broadcast via shfl: lane qrow (hi=0 image) owns invz for q-row qrow.
  float izv[4][4];
  #pragma unroll
  for (int g=0; g<4; g++)
    #pragma unroll
    for (int r=0; r<4; r++)
      izv[g][r] = __shfl(invz, 8*g + 4*hi + r);

  // O write, head-major [B,H,S,D] (C: col=d-within-32, row=(reg&3)+8*(reg>>2)+4*hi)
  u16* obase = attnb + ((size_t)bh*CS + q0w)*CD;
  #pragma unroll
  for (int nt=0;nt<2;nt++){
    #pragma unroll
    for (int g=0;g<4;g++){
      #pragma unroll
      for (int r=0;r<4;r++){
        int qrow = 8*g + 4*hi + r;
        obase[(size_t)qrow*CD + nt*32 + col] = f2bf(o[nt][g*4+r] * izv[g][r]);
      }
    }
  }
}

// ---------------------------------------------------------------------------
// GEMM3 (R10-exact): A direct global->VGPR prefetch; B 3-buffer counted-vmcnt
// LDS pipeline (24 KiB), BK=32, launch_bounds(256,3).
// attnH is head-major [B,H,S,D]; K-tile kk = head kk>>1, d-half (kk&1)*32.
// ---------------------------------------------------------------------------
__global__ __launch_bounds__(256, 3) void gemm_out_kernel(
    const u16* __restrict__ attnH, const u16* __restrict__ wprojT,
    float* __restrict__ out){
  __shared__ __align__(16) u16 bl[3][128*32];
  int t = threadIdx.x;
  int wv = t >> 6, lane = t & 63, lo = lane & 15, q4 = lane >> 4;
  int m0 = blockIdx.x * 128;
  int n0 = blockIdx.y * 128;
  int b  = m0 >> 11, s0 = m0 & (CS-1);
  int lsB = (lane & 3) ^ ((lane >> 3) & 3);
  const u16* bg0 = wprojT + (size_t)(n0 + (lane>>2))*CC + lsB*8;
  // A base for this lane's rows (head/d-half offset added per kk)
  const u16* agl0 = attnH + ((size_t)(b*CH)*CS + s0 + wv*32 + lo)*CD + q4*8;
  const u16* agl1 = agl0 + (size_t)16*CD;

  f32x4 acc[2][8];
  #pragma unroll
  for (int i=0;i<2;i++)
    #pragma unroll
    for (int j=0;j<8;j++) acc[i][j] = (f32x4){0.f,0.f,0.f,0.f};

  auto aoff = [&](int kk) -> size_t {
    return (size_t)(kk >> 1)*CS*CD + (size_t)(kk & 1)*32;
  };
  auto stageB = [&](int buf, int kk){
    #pragma unroll
    for (int cc=0; cc<2; cc++){
      int c = wv*2 + cc;
      gload16(bg0 + (size_t)c*16*CC + kk*32, &bl[buf][c*512]);
    }
  };

  stageB(0, 0);
  stageB(1, 1);
  bf16x8 acur0 = *(const bf16x8*)(agl0);
  bf16x8 acur1 = *(const bf16x8*)(agl1);
  int cur = 0;
  const int akey = (lo >> 1) & 3;

  for (int kk = 0; kk < 32; kk++){
    if (kk < 30){
      asm volatile("s_waitcnt vmcnt(4)" ::: "memory");
      __builtin_amdgcn_s_barrier();
      __builtin_amdgcn_sched_barrier(0);
      int nb = cur + 2; if (nb >= 3) nb -= 3;
      stageB(nb, kk + 2);
    } else if (kk == 30){
      asm volatile("s_waitcnt vmcnt(4)" ::: "memory");
      __builtin_amdgcn_s_barrier();
      __builtin_amdgcn_sched_barrier(0);
    } else {
      asm volatile("s_waitcnt vmcnt(0)" ::: "memory");
      __builtin_amdgcn_s_barrier();
      __builtin_amdgcn_sched_barrier(0);
    }
    bf16x8 anxt0, anxt1;
    if (kk < 31){
      size_t ao = aoff(kk + 1);
      anxt0 = *(const bf16x8*)(agl0 + ao);
      anxt1 = *(const bf16x8*)(agl1 + ao);
    } else {
      anxt0 = acur0; anxt1 = acur1;
    }
    const u16* bc = &bl[cur][0];
    int soff = (q4 ^ akey) << 3;
    __builtin_amdgcn_s_setprio(1);
    #pragma unroll
    for (int nt=0; nt<8; nt++){
      bf16x8 b2 = *(const bf16x8*)&bc[(nt*16 + lo)*32 + soff];
      acc[0][nt] = mfma16(acur0, b2, acc[0][nt]);
      acc[1][nt] = mfma16(acur1, b2, acc[1][nt]);
    }
    __builtin_amdgcn_s_setprio(0);
    acur0 = anxt0; acur1 = anxt1;
    cur = (cur == 2) ? 0 : cur + 1;
  }

  for (int rt=0;rt<2;rt++){
    for (int r=0;r<4;r++){
      int row = m0 + wv*32 + rt*16 + q4*4 + r;
      for (int nt=0;nt<8;nt++)
        out[(size_t)row*CC + n0 + nt*16 + lo] = acc[rt][nt][r];
    }
  }
}

// ---------------------------------------------------------------------------
extern "C" void kernel_launch(void* const* d_in, const int* in_sizes, int n_in,
                              void* d_out, int out_size, void* d_ws, size_t ws_size,
                              hipStream_t stream) {
  const float* x      = (const float*)d_in[0];
  const float* w_qkv  = (const float*)d_in[1];
  const float* w_proj = (const float*)d_in[2];
  const float* q_scale= (const float*)d_in[3];
  const float* q_bias = (const float*)d_in[4];
  const float* k_scale= (const float*)d_in[5];
  const float* k_bias = (const float*)d_in[6];
  float* out = (float*)d_out;
  float* ent = out + (size_t)CBS * CC;

  // workspace: 72 MB. vbT is written directly transposed by gemm_qkv (no
  // transpose_v kernel). attn aliases xb (dead after gemm_qkv).
  u16* xb     = (u16*)d_ws;                       // [8192][1024]  (later: attnH)
  u16* wqkvT  = xb     + (size_t)CBS*CC;          // [3072][1024]
  u16* wprojT = wqkvT  + (size_t)3*CC*CC;         // [1024][1024]
  u16* qb     = wprojT + (size_t)CC*CC;           // [B,H,S,D]
  u16* kb     = qb  + (size_t)CB*CH*CS*CD;        // [B,H,S,D]
  u16* vbT    = kb  + (size_t)CB*CH*CS*CD;        // [B,H,D,S]
  u16* attn   = xb;                               // alias

  convert_x_kernel<<<dim3(CBS*CC/(256*8)), 256, 0, stream>>>(x, xb, ent);
  transpose_convert_kernel<CC, 3*CC><<<dim3((CC/64)*(3*CC/64)), 256, 0, stream>>>(w_qkv, wqkvT);
  transpose_convert_kernel<CC, CC><<<dim3((CC/64)*(CC/64)), 256, 0, stream>>>(w_proj, wprojT);
  gemm_qkv_ln_kernel<<<dim3(CBS/128, 3*CC/128), 256, 0, stream>>>(
      xb, wqkvT, q_scale, q_bias, k_scale, k_bias, qb, kb, vbT);
  attention_kernel<<<dim3(CB*CH*(CS/128)), 256, 0, stream>>>(qb, kb, vbT, attn, ent);
  gemm_out_kernel<<<dim3(CBS/128, CC/128), 256, 0, stream>>>(attn, wprojT, out);
}